// Round 1
// baseline (252.872 us; speedup 1.0000x reference)
//
#include <hip/hip_runtime.h>
#include <math.h>

#define N_NODES 50000
#define N_EDGES 800000
#define ET (N_EDGES + N_NODES)   // 850000 incl. self-loops
#define KD 128
#define Z 32
#define SH 7
#define BW 128                              // nodes per bucket
#define NBUCK ((N_NODES + BW - 1) / BW)     // 391
#define CHUNK 4096
#define NBLKA ((ET + CHUNK - 1) / CHUNK)    // 208 chunks
#define MTOT (NBUCK * NBLKA)                // 81,328
#define MBS ((MTOT + 1023) / 1024)          // 80

typedef __attribute__((ext_vector_type(8))) short bf16x8;
typedef __attribute__((ext_vector_type(4))) float f32x4;

static __device__ __forceinline__ float lrelu(float x){ return x > 0.f ? x : 0.2f*x; }
static __device__ __forceinline__ float bf2f(unsigned int u16){ return __uint_as_float(u16 << 16); }
static __device__ __forceinline__ float lof(unsigned int u){ return __uint_as_float(u << 16); }
static __device__ __forceinline__ float hif(unsigned int u){ return __uint_as_float(u & 0xffff0000u); }
static __device__ __forceinline__ unsigned short f2bf(float f){
  unsigned int x = __float_as_uint(f);
  return (unsigned short)((x + 0x7fffu + ((x >> 16) & 1u)) >> 16);   // RNE
}

// ---------- CSR build: counting sort, NO global atomics ----------
__global__ __launch_bounds__(256) void bhistA_kernel(const int* __restrict__ edges, int* __restrict__ M){
  int k = blockIdx.x, t = threadIdx.x;
  __shared__ int cnt[NBUCK];
  for(int b = t; b < NBUCK; b += 256) cnt[b] = 0;
  __syncthreads();
  int base = k*CHUNK;
  int lim = min(base + CHUNK, ET);
  for(int i = base + t; i < lim; i += 256){
    int d = (i < N_EDGES) ? edges[N_EDGES + i] : (i - N_EDGES);
    atomicAdd(&cnt[d >> SH], 1);
  }
  __syncthreads();
  for(int b = t; b < NBUCK; b += 256) M[b*NBLKA + k] = cnt[b];
}

__global__ __launch_bounds__(256) void scanM1_kernel(const int* __restrict__ M, int* __restrict__ bsumM){
  int b = blockIdx.x, t = threadIdx.x;
  int base = b*1024 + t*4;
  int s = 0;
  #pragma unroll
  for(int i=0;i<4;i++){ int n = base+i; if(n < MTOT) s += M[n]; }
  for(int off=32; off; off>>=1) s += __shfl_xor(s, off);
  __shared__ int ws[4];
  if((t&63)==0) ws[t>>6] = s;
  __syncthreads();
  if(t==0) bsumM[b] = ws[0]+ws[1]+ws[2]+ws[3];
}

__global__ __launch_bounds__(256) void scanM2_kernel(const int* __restrict__ bsumM, int* __restrict__ bpreM){
  __shared__ int sm[256];
  int t = threadIdx.x;
  int v = (t < MBS) ? bsumM[t] : 0;
  sm[t] = v;
  __syncthreads();
  for(int off=1; off<256; off<<=1){
    int u = (t >= off) ? sm[t-off] : 0;
    __syncthreads();
    sm[t] += u;
    __syncthreads();
  }
  if(t < MBS) bpreM[t] = sm[t] - v;
}

__global__ __launch_bounds__(256) void scanM3_kernel(const int* __restrict__ M, const int* __restrict__ bpreM,
                                                     int* __restrict__ Mpos){
  int b = blockIdx.x, t = threadIdx.x;
  int lane = t & 63, wv = t >> 6;
  int base = b*1024 + t*4;
  int d[4]; int s = 0;
  #pragma unroll
  for(int i=0;i<4;i++){ int n = base+i; d[i] = (n < MTOT) ? M[n] : 0; s += d[i]; }
  int v = s;
  for(int off=1; off<64; off<<=1){
    int u = __shfl_up(v, off);
    if(lane >= off) v += u;
  }
  int texcl = v - s;
  __shared__ int wtot[4];
  if(lane == 63) wtot[wv] = v;
  __syncthreads();
  int woff = 0;
  for(int i=0;i<wv;i++) woff += wtot[i];
  int run = bpreM[b] + woff + texcl;
  #pragma unroll
  for(int i=0;i<4;i++){
    int n = base+i;
    if(n < MTOT){ Mpos[n] = run; run += d[i]; }
  }
}

__global__ __launch_bounds__(256) void bplaceA_kernel(const int* __restrict__ edges, const int* __restrict__ Mpos,
                                                      int2* __restrict__ etmp){
  int k = blockIdx.x, t = threadIdx.x;
  __shared__ int cur[NBUCK];
  for(int b = t; b < NBUCK; b += 256) cur[b] = Mpos[b*NBLKA + k];
  __syncthreads();
  int base = k*CHUNK;
  int lim = min(base + CHUNK, ET);
  for(int i = base + t; i < lim; i += 256){
    int s, d;
    if(i < N_EDGES){ s = edges[i]; d = edges[N_EDGES+i]; } else { s = d = i - N_EDGES; }
    int pos = atomicAdd(&cur[d >> SH], 1);
    etmp[pos] = make_int2(s, d);
  }
}

// fused: per-bucket node histogram + local scan -> rowptr + in-bucket place -> esrc + edst
__global__ __launch_bounds__(256) void bfin_kernel(const int* __restrict__ Mpos, const int2* __restrict__ etmp,
                                                   int* __restrict__ rowptr, int* __restrict__ esrc,
                                                   int* __restrict__ edst){
  int b = blockIdx.x, t = threadIdx.x;
  __shared__ int cnt[BW];
  __shared__ int pre[BW];
  __shared__ int lcur[BW];
  if(t < BW) cnt[t] = 0;
  __syncthreads();
  int beg = Mpos[b*NBLKA];
  int end = (b+1 < NBUCK) ? Mpos[(b+1)*NBLKA] : ET;
  for(int i = beg + t; i < end; i += 256) atomicAdd(&cnt[etmp[i].y & (BW-1)], 1);
  __syncthreads();
  if(t < BW) pre[t] = cnt[t];
  __syncthreads();
  for(int off=1; off<BW; off<<=1){
    int u = 0;
    if(t < BW && t >= off) u = pre[t-off];
    __syncthreads();
    if(t < BW) pre[t] += u;
    __syncthreads();
  }
  if(t < BW){
    int excl = pre[t] - cnt[t];
    int node = b*BW + t;
    if(node < N_NODES) rowptr[node] = beg + excl;
    lcur[t] = beg + excl;
  }
  if(b == 0 && t == 255) rowptr[N_NODES] = ET;
  __syncthreads();
  for(int i = beg + t; i < end; i += 256){
    int2 e = etmp[i];
    int pos = atomicAdd(&lcur[e.y & (BW-1)], 1);
    esrc[pos] = e.x;
    edst[pos] = e.y;
  }
}

// ---------- W -> bf16 converter ----------
__global__ __launch_bounds__(256) void wconv_kernel(const float* __restrict__ W1,
                                                    const float* __restrict__ Wmu, const float* __restrict__ Wst,
                                                    unsigned short* __restrict__ Wb1, unsigned short* __restrict__ Wb2){
  int i = blockIdx.x*256 + threadIdx.x;
  if(i < 128*KD) Wb1[i] = f2bf(W1[i]);
  if(i < 64*KD) Wb2[i] = f2bf(i < 32*KD ? Wmu[i] : Wst[i - 32*KD]);
}

// ---------- MFMA matmul layer1 (OC=128) + fused alpha1 ----------
__global__ __launch_bounds__(256) void mmt1_kernel(const float* __restrict__ X,
                                                   const unsigned short* __restrict__ Wb,
                                                   const float* __restrict__ asv, const float* __restrict__ adv,
                                                   unsigned short* __restrict__ outb,
                                                   float* __restrict__ as1, float* __restrict__ ad1){
  constexpr int OC = 128, CT = 8;
  int t = threadIdx.x;
  int w = t >> 6, L = t & 63;
  int col = L & 15, quad = L >> 4;
  int row0 = blockIdx.x*64 + w*16;
  int rA = row0 + col;
  if(rA >= N_NODES) rA = N_NODES-1;

  f32x4 acc[CT];
  #pragma unroll
  for(int ct=0;ct<CT;ct++) acc[ct] = (f32x4){0.f,0.f,0.f,0.f};

  #pragma unroll
  for(int kc=0;kc<4;kc++){
    int k0 = kc*32 + quad*8;
    const float* Xf = X + (size_t)rA*KD + k0;
    float4 p = *(const float4*)Xf;
    float4 q = *(const float4*)(Xf + 4);
    bf16x8 a;
    a[0] = (short)f2bf(p.x); a[1] = (short)f2bf(p.y);
    a[2] = (short)f2bf(p.z); a[3] = (short)f2bf(p.w);
    a[4] = (short)f2bf(q.x); a[5] = (short)f2bf(q.y);
    a[6] = (short)f2bf(q.z); a[7] = (short)f2bf(q.w);
    #pragma unroll
    for(int ct=0;ct<CT;ct++){
      bf16x8 b = *(const bf16x8*)(Wb + (size_t)(ct*16 + col)*KD + k0);
      acc[ct] = __builtin_amdgcn_mfma_f32_16x16x32_bf16(a, b, acc[ct], 0, 0, 0);
    }
  }

  float av[CT], dv[CT];
  #pragma unroll
  for(int ct=0;ct<CT;ct++){ av[ct] = asv[ct*16 + col]; dv[ct] = adv[ct*16 + col]; }

  #pragma unroll
  for(int r=0;r<4;r++){
    int row = row0 + quad*4 + r;
    #pragma unroll
    for(int ct=0;ct<CT;ct++)
      if(row < N_NODES) outb[(size_t)row*OC + ct*16 + col] = f2bf(acc[ct][r]);
    float s0 = acc[0][r]*av[0] + acc[1][r]*av[1] + acc[2][r]*av[2] + acc[3][r]*av[3];
    float s1 = acc[4][r]*av[4] + acc[5][r]*av[5] + acc[6][r]*av[6] + acc[7][r]*av[7];
    float d0 = acc[0][r]*dv[0] + acc[1][r]*dv[1] + acc[2][r]*dv[2] + acc[3][r]*dv[3];
    float d1 = acc[4][r]*dv[4] + acc[5][r]*dv[5] + acc[6][r]*dv[6] + acc[7][r]*dv[7];
    #pragma unroll
    for(int off=1; off<16; off<<=1){
      s0 += __shfl_xor(s0, off); s1 += __shfl_xor(s1, off);
      d0 += __shfl_xor(d0, off); d1 += __shfl_xor(d1, off);
    }
    if(col == 0 && row < N_NODES){
      as1[row*2] = s0; as1[row*2+1] = s1;
      ad1[row*2] = d0; ad1[row*2+1] = d1;
    }
  }
}

// ---------- MFMA matmul layer2 (OC=64, bf16 X) + fused alpha2 ----------
__global__ __launch_bounds__(256) void mmt2_kernel(const unsigned short* __restrict__ Xb,
                                                   const unsigned short* __restrict__ Wb,
                                                   const float* __restrict__ asmu, const float* __restrict__ admu,
                                                   const float* __restrict__ asst, const float* __restrict__ adst,
                                                   unsigned short* __restrict__ outb,
                                                   float* __restrict__ as2, float* __restrict__ ad2){
  constexpr int OC = 64, CT = 4;
  int t = threadIdx.x;
  int w = t >> 6, L = t & 63;
  int col = L & 15, quad = L >> 4;
  int row0 = blockIdx.x*64 + w*16;
  int rA = row0 + col;
  if(rA >= N_NODES) rA = N_NODES-1;

  f32x4 acc[CT];
  #pragma unroll
  for(int ct=0;ct<CT;ct++) acc[ct] = (f32x4){0.f,0.f,0.f,0.f};

  #pragma unroll
  for(int kc=0;kc<4;kc++){
    int k0 = kc*32 + quad*8;
    bf16x8 a = *(const bf16x8*)(Xb + (size_t)rA*KD + k0);
    #pragma unroll
    for(int ct=0;ct<CT;ct++){
      bf16x8 b = *(const bf16x8*)(Wb + (size_t)(ct*16 + col)*KD + k0);
      acc[ct] = __builtin_amdgcn_mfma_f32_16x16x32_bf16(a, b, acc[ct], 0, 0, 0);
    }
  }

  float av[CT], dv[CT];
  #pragma unroll
  for(int ct=0;ct<CT;ct++){
    av[ct] = (ct < 2) ? asmu[ct*16 + col] : asst[(ct-2)*16 + col];
    dv[ct] = (ct < 2) ? admu[ct*16 + col] : adst[(ct-2)*16 + col];
  }

  #pragma unroll
  for(int r=0;r<4;r++){
    int row = row0 + quad*4 + r;
    #pragma unroll
    for(int ct=0;ct<CT;ct++)
      if(row < N_NODES) outb[(size_t)row*OC + ct*16 + col] = f2bf(acc[ct][r]);
    float smu = acc[0][r]*av[0] + acc[1][r]*av[1];
    float sst = acc[2][r]*av[2] + acc[3][r]*av[3];
    float dmu = acc[0][r]*dv[0] + acc[1][r]*dv[1];
    float dst = acc[2][r]*dv[2] + acc[3][r]*dv[3];
    #pragma unroll
    for(int off=1; off<16; off<<=1){
      smu += __shfl_xor(smu, off); sst += __shfl_xor(sst, off);
      dmu += __shfl_xor(dmu, off); dst += __shfl_xor(dst, off);
    }
    if(col == 0 && row < N_NODES){
      as2[row*2] = smu; as2[row*2+1] = sst;
      ad2[row*2] = dmu; ad2[row*2+1] = dst;
    }
  }
}

// ---------- edge-parallel softmax-weight precompute ----------
// One thread per edge: w[i] = exp(lrelu(as[src] + ad[dst])) for both heads.
// Removes the 64x (agg1) / 16x (agg2) lane-redundant exp+lrelu from the agg kernels.
__global__ __launch_bounds__(256) void wcalc_kernel(const int* __restrict__ esrc, const int* __restrict__ edst,
                                                    const float* __restrict__ as, const float* __restrict__ ad,
                                                    float2* __restrict__ wp){
  int i = blockIdx.x*256 + threadIdx.x;
  if(i >= ET) return;
  int s = esrc[i], d = edst[i];
  float2 a = ((const float2*)as)[s];
  float2 b = ((const float2*)ad)[d];
  wp[i] = make_float2(__expf(lrelu(a.x + b.x)), __expf(lrelu(a.y + b.y)));
}

// ---------- agg layer 1: full-wave uint gathers, precomputed weights ----------
__global__ __launch_bounds__(256) void agg1_kernel(const int* __restrict__ rowptr, const int* __restrict__ esrc,
                                                   const float2* __restrict__ wp,
                                                   const unsigned int* __restrict__ xb,
                                                   const float* __restrict__ b1, unsigned int* __restrict__ hb){
  int node = blockIdx.x*4 + (threadIdx.x>>6);
  int l = threadIdx.x & 63;
  if(node >= N_NODES) return;
  int beg = rowptr[node], end = rowptr[node+1];
  float accx = 0.f, accy = 0.f, s0 = 0.f, s1 = 0.f;
  int n = end - beg;
  int nq = n & ~7;

#define F1_E(j)  int e##j = esrc[i+j];
#define F1_W(j)  float2 w##j = wp[i+j];
#define F1_U(j)  unsigned int u##j = xb[(size_t)e##j*64 + l];
#define F1_C(j)  { s0 += w##j.x; s1 += w##j.y; \
                   float vv = (l < 32) ? w##j.x : w##j.y; \
                   accx += vv * lof(u##j); accy += vv * hif(u##j); }

  for(int i = beg; i < beg + nq; i += 8){
    F1_E(0) F1_E(1) F1_E(2) F1_E(3) F1_E(4) F1_E(5) F1_E(6) F1_E(7)
    F1_W(0) F1_W(1) F1_W(2) F1_W(3) F1_W(4) F1_W(5) F1_W(6) F1_W(7)
    F1_U(0) F1_U(1) F1_U(2) F1_U(3) F1_U(4) F1_U(5) F1_U(6) F1_U(7)
    F1_C(0) F1_C(1) F1_C(2) F1_C(3) F1_C(4) F1_C(5) F1_C(6) F1_C(7)
  }
  for(int i = beg + nq; i < end; i++){
    F1_E(0) F1_W(0) F1_U(0) F1_C(0)
  }
#undef F1_E
#undef F1_W
#undef F1_U
#undef F1_C
  float sd = (l < 32) ? s0 : s1;
  float2 bb = ((const float2*)b1)[l];
  float rx = fmaxf(accx/sd + bb.x, 0.f);
  float ry = fmaxf(accy/sd + bb.y, 0.f);
  unsigned int hp = (unsigned int)f2bf(rx) | ((unsigned int)f2bf(ry) << 16);
  hb[(size_t)node*64 + l] = hp;
}

// ---------- agg layer 2: 4 edges/instr (16-lane groups), uint2 gathers, precomputed weights ----------
__global__ __launch_bounds__(256) void agg2_kernel(const int* __restrict__ rowptr, const int* __restrict__ esrc,
                                                   const float2* __restrict__ wp,
                                                   const uint2* __restrict__ xb2,
                                                   const float* __restrict__ bmu, const float* __restrict__ bst,
                                                   float* __restrict__ out){
  int node = blockIdx.x*4 + (threadIdx.x>>6);
  int l = threadIdx.x & 63;
  if(node >= N_NODES) return;
  int g = l >> 4, c = l & 15;        // lane handles features 4c..4c+3 of edge (i+g)
  int beg = rowptr[node], end = rowptr[node+1];
  int n = end - beg;
  float a0=0.f, a1=0.f, a2=0.f, a3=0.f, smu=0.f, sst=0.f;
  int nquad = n >> 2;
  int mainq = nquad & ~3;

#define G2(j) int e##j = esrc[base + 4*j]; float2 w##j = wp[base + 4*j];
#define U2(j) uint2 u##j = xb2[(size_t)e##j*16 + c];
#define C2(j) { smu += w##j.x; sst += w##j.y; \
                float vv = (c < 8) ? w##j.x : w##j.y; \
                a0 += vv*lof(u##j.x); a1 += vv*hif(u##j.x); \
                a2 += vv*lof(u##j.y); a3 += vv*hif(u##j.y); }

  for(int qq = 0; qq < mainq; qq += 4){
    int base = beg + 4*qq + g;
    G2(0) G2(1) G2(2) G2(3)
    U2(0) U2(1) U2(2) U2(3)
    C2(0) C2(1) C2(2) C2(3)
  }
  for(int qq = mainq; qq < nquad; qq++){
    int base = beg + 4*qq + g;
    G2(0) U2(0) C2(0)
  }
  int tail = n & 3;
  if(g < tail){
    int idx = beg + 4*nquad + g;
    int e = esrc[idx];
    float2 w = wp[idx];
    uint2 u = xb2[(size_t)e*16 + c];
    smu += w.x; sst += w.y;
    float vv = (c < 8) ? w.x : w.y;
    a0 += vv*lof(u.x); a1 += vv*hif(u.x);
    a2 += vv*lof(u.y); a3 += vv*hif(u.y);
  }
#undef G2
#undef U2
#undef C2
  #pragma unroll
  for(int off = 16; off < 64; off <<= 1){
    smu += __shfl_xor(smu, off); sst += __shfl_xor(sst, off);
    a0 += __shfl_xor(a0, off); a1 += __shfl_xor(a1, off);
    a2 += __shfl_xor(a2, off); a3 += __shfl_xor(a3, off);
  }
  float sd = (c < 8) ? smu : sst;
  float4 bb = (c < 8) ? *(const float4*)(bmu + 4*c) : *(const float4*)(bst + 4*(c-8));
  float4 r;
  r.x = a0/sd + bb.x;
  r.y = a1/sd + bb.y;
  r.z = a2/sd + bb.z;
  r.w = a3/sd + bb.w;
  if(g == 0){
    float* dst = (c < 8) ? (out + (size_t)node*Z + 4*c)
                         : (out + (size_t)N_NODES*Z + (size_t)node*Z + 4*(c-8));
    *(float4*)dst = r;
  }
}

extern "C" void kernel_launch(void* const* d_in, const int* in_sizes, int n_in,
                              void* d_out, int out_size, void* d_ws, size_t ws_size,
                              hipStream_t stream){
  const float* x    = (const float*)d_in[0];
  const int*   edges= (const int*)d_in[1];
  const float* W1   = (const float*)d_in[2];
  const float* as1v = (const float*)d_in[3];
  const float* ad1v = (const float*)d_in[4];
  const float* b1   = (const float*)d_in[5];
  const float* Wmu  = (const float*)d_in[6];
  const float* asmu = (const float*)d_in[7];
  const float* admu = (const float*)d_in[8];
  const float* bmu  = (const float*)d_in[9];
  const float* Wst  = (const float*)d_in[10];
  const float* asst = (const float*)d_in[11];
  const float* adst = (const float*)d_in[12];
  const float* bst  = (const float*)d_in[13];
  float* out = (float*)d_out;

  char* p = (char*)d_ws;
  auto alloc = [&](size_t bytes)->char*{ char* r = p; p += (bytes + 255) & ~size_t(255); return r; };
  int*   M      = (int*)  alloc((size_t)MTOT*4);
  int*   Mpos   = (int*)  alloc((size_t)MTOT*4);
  int*   bsumM  = (int*)  alloc((size_t)MBS*4);
  int*   bpreM  = (int*)  alloc((size_t)MBS*4);
  int2*  etmp   = (int2*) alloc((size_t)ET*8);
  int*   esrc   = (int*)  alloc((size_t)ET*4);
  int*   edst   = (int*)  alloc((size_t)ET*4);
  int*   rowptr = (int*)  alloc((size_t)(N_NODES+1)*4);
  unsigned short* Wb1 = (unsigned short*)alloc((size_t)128*KD*2);
  unsigned short* Wb2 = (unsigned short*)alloc((size_t)64*KD*2);
  unsigned short* xpb1 = (unsigned short*)alloc((size_t)N_NODES*128*2);
  float* as1    = (float*)alloc((size_t)N_NODES*2*4);
  float* ad1    = (float*)alloc((size_t)N_NODES*2*4);
  unsigned short* hb = (unsigned short*)alloc((size_t)N_NODES*128*2);
  float* as2    = (float*)alloc((size_t)N_NODES*2*4);
  float* ad2    = (float*)alloc((size_t)N_NODES*2*4);
  unsigned short* xpb2 = xpb1;                          // xpb1 dead after agg1
  float2* wedge = (float2*)etmp;                        // etmp dead after bfin; ET*8 bytes, reused per layer

  bhistA_kernel  <<<NBLKA, 256, 0, stream>>>(edges, M);
  scanM1_kernel  <<<MBS, 256, 0, stream>>>(M, bsumM);
  scanM2_kernel  <<<1, 256, 0, stream>>>(bsumM, bpreM);
  scanM3_kernel  <<<MBS, 256, 0, stream>>>(M, bpreM, Mpos);
  bplaceA_kernel <<<NBLKA, 256, 0, stream>>>(edges, Mpos, etmp);
  bfin_kernel    <<<NBUCK, 256, 0, stream>>>(Mpos, etmp, rowptr, esrc, edst);

  wconv_kernel   <<<(128*KD + 255)/256, 256, 0, stream>>>(W1, Wmu, Wst, Wb1, Wb2);

  mmt1_kernel  <<<(N_NODES+63)/64, 256, 0, stream>>>(x, Wb1, as1v, ad1v, xpb1, as1, ad1);
  wcalc_kernel <<<(ET+255)/256, 256, 0, stream>>>(esrc, edst, as1, ad1, wedge);
  agg1_kernel  <<<(N_NODES+3)/4, 256, 0, stream>>>(rowptr, esrc, wedge, (const unsigned int*)xpb1, b1, (unsigned int*)hb);

  mmt2_kernel  <<<(N_NODES+63)/64, 256, 0, stream>>>(hb, Wb2, asmu, admu, asst, adst, xpb1, as2, ad2);
  wcalc_kernel <<<(ET+255)/256, 256, 0, stream>>>(esrc, edst, as2, ad2, wedge);
  agg2_kernel  <<<(N_NODES+3)/4, 256, 0, stream>>>(rowptr, esrc, wedge, (const uint2*)xpb2, bmu, bst, out);
}

// Round 2
// 250.147 us; speedup vs baseline: 1.0109x; 1.0109x over previous
//
#include <hip/hip_runtime.h>
#include <math.h>

#define N_NODES 50000
#define N_EDGES 800000
#define ET (N_EDGES + N_NODES)   // 850000 incl. self-loops
#define KD 128
#define Z 32
#define SH 7
#define BW 128                              // nodes per bucket
#define NBUCK ((N_NODES + BW - 1) / BW)     // 391
#define CHUNK 4096
#define NBLKA ((ET + CHUNK - 1) / CHUNK)    // 208 chunks
#define MTOT (NBUCK * NBLKA)                // 81,328
#define MBS ((MTOT + 1023) / 1024)          // 80

typedef __attribute__((ext_vector_type(8))) short bf16x8;
typedef __attribute__((ext_vector_type(4))) float f32x4;

static __device__ __forceinline__ float lrelu(float x){ return x > 0.f ? x : 0.2f*x; }
static __device__ __forceinline__ float bf2f(unsigned int u16){ return __uint_as_float(u16 << 16); }
static __device__ __forceinline__ float lof(unsigned int u){ return __uint_as_float(u << 16); }
static __device__ __forceinline__ float hif(unsigned int u){ return __uint_as_float(u & 0xffff0000u); }
static __device__ __forceinline__ unsigned short f2bf(float f){
  unsigned int x = __float_as_uint(f);
  return (unsigned short)((x + 0x7fffu + ((x >> 16) & 1u)) >> 16);   // RNE
}

// ---------- CSR build: counting sort, NO global atomics ----------
__global__ __launch_bounds__(256) void bhistA_kernel(const int* __restrict__ edges, int* __restrict__ M){
  int k = blockIdx.x, t = threadIdx.x;
  __shared__ int cnt[NBUCK];
  for(int b = t; b < NBUCK; b += 256) cnt[b] = 0;
  __syncthreads();
  int base = k*CHUNK;
  int lim = min(base + CHUNK, ET);
  for(int i = base + t; i < lim; i += 256){
    int d = (i < N_EDGES) ? edges[N_EDGES + i] : (i - N_EDGES);
    atomicAdd(&cnt[d >> SH], 1);
  }
  __syncthreads();
  for(int b = t; b < NBUCK; b += 256) M[b*NBLKA + k] = cnt[b];
}

__global__ __launch_bounds__(256) void scanM1_kernel(const int* __restrict__ M, int* __restrict__ bsumM){
  int b = blockIdx.x, t = threadIdx.x;
  int base = b*1024 + t*4;
  int s = 0;
  #pragma unroll
  for(int i=0;i<4;i++){ int n = base+i; if(n < MTOT) s += M[n]; }
  for(int off=32; off; off>>=1) s += __shfl_xor(s, off);
  __shared__ int ws[4];
  if((t&63)==0) ws[t>>6] = s;
  __syncthreads();
  if(t==0) bsumM[b] = ws[0]+ws[1]+ws[2]+ws[3];
}

__global__ __launch_bounds__(256) void scanM2_kernel(const int* __restrict__ bsumM, int* __restrict__ bpreM){
  __shared__ int sm[256];
  int t = threadIdx.x;
  int v = (t < MBS) ? bsumM[t] : 0;
  sm[t] = v;
  __syncthreads();
  for(int off=1; off<256; off<<=1){
    int u = (t >= off) ? sm[t-off] : 0;
    __syncthreads();
    sm[t] += u;
    __syncthreads();
  }
  if(t < MBS) bpreM[t] = sm[t] - v;
}

__global__ __launch_bounds__(256) void scanM3_kernel(const int* __restrict__ M, const int* __restrict__ bpreM,
                                                     int* __restrict__ Mpos){
  int b = blockIdx.x, t = threadIdx.x;
  int lane = t & 63, wv = t >> 6;
  int base = b*1024 + t*4;
  int d[4]; int s = 0;
  #pragma unroll
  for(int i=0;i<4;i++){ int n = base+i; d[i] = (n < MTOT) ? M[n] : 0; s += d[i]; }
  int v = s;
  for(int off=1; off<64; off<<=1){
    int u = __shfl_up(v, off);
    if(lane >= off) v += u;
  }
  int texcl = v - s;
  __shared__ int wtot[4];
  if(lane == 63) wtot[wv] = v;
  __syncthreads();
  int woff = 0;
  for(int i=0;i<wv;i++) woff += wtot[i];
  int run = bpreM[b] + woff + texcl;
  #pragma unroll
  for(int i=0;i<4;i++){
    int n = base+i;
    if(n < MTOT){ Mpos[n] = run; run += d[i]; }
  }
}

__global__ __launch_bounds__(256) void bplaceA_kernel(const int* __restrict__ edges, const int* __restrict__ Mpos,
                                                      int2* __restrict__ etmp){
  int k = blockIdx.x, t = threadIdx.x;
  __shared__ int cur[NBUCK];
  for(int b = t; b < NBUCK; b += 256) cur[b] = Mpos[b*NBLKA + k];
  __syncthreads();
  int base = k*CHUNK;
  int lim = min(base + CHUNK, ET);
  for(int i = base + t; i < lim; i += 256){
    int s, d;
    if(i < N_EDGES){ s = edges[i]; d = edges[N_EDGES+i]; } else { s = d = i - N_EDGES; }
    int pos = atomicAdd(&cur[d >> SH], 1);
    etmp[pos] = make_int2(s, d);
  }
}

// fused: per-bucket node histogram + local scan -> rowptr + in-bucket place -> esrc + edst
__global__ __launch_bounds__(256) void bfin_kernel(const int* __restrict__ Mpos, const int2* __restrict__ etmp,
                                                   int* __restrict__ rowptr, int* __restrict__ esrc,
                                                   int* __restrict__ edst){
  int b = blockIdx.x, t = threadIdx.x;
  __shared__ int cnt[BW];
  __shared__ int pre[BW];
  __shared__ int lcur[BW];
  if(t < BW) cnt[t] = 0;
  if(b == 0 && t < 32) esrc[ET + t] = 0;     // zero pad: agg kernels overread up to +16
  __syncthreads();
  int beg = Mpos[b*NBLKA];
  int end = (b+1 < NBUCK) ? Mpos[(b+1)*NBLKA] : ET;
  for(int i = beg + t; i < end; i += 256) atomicAdd(&cnt[etmp[i].y & (BW-1)], 1);
  __syncthreads();
  if(t < BW) pre[t] = cnt[t];
  __syncthreads();
  for(int off=1; off<BW; off<<=1){
    int u = 0;
    if(t < BW && t >= off) u = pre[t-off];
    __syncthreads();
    if(t < BW) pre[t] += u;
    __syncthreads();
  }
  if(t < BW){
    int excl = pre[t] - cnt[t];
    int node = b*BW + t;
    if(node < N_NODES) rowptr[node] = beg + excl;
    lcur[t] = beg + excl;
  }
  if(b == 0 && t == 255) rowptr[N_NODES] = ET;
  __syncthreads();
  for(int i = beg + t; i < end; i += 256){
    int2 e = etmp[i];
    int pos = atomicAdd(&lcur[e.y & (BW-1)], 1);
    esrc[pos] = e.x;
    edst[pos] = e.y;
  }
}

// ---------- W -> bf16 converter ----------
__global__ __launch_bounds__(256) void wconv_kernel(const float* __restrict__ W1,
                                                    const float* __restrict__ Wmu, const float* __restrict__ Wst,
                                                    unsigned short* __restrict__ Wb1, unsigned short* __restrict__ Wb2){
  int i = blockIdx.x*256 + threadIdx.x;
  if(i < 128*KD) Wb1[i] = f2bf(W1[i]);
  if(i < 64*KD) Wb2[i] = f2bf(i < 32*KD ? Wmu[i] : Wst[i - 32*KD]);
}

// ---------- MFMA matmul layer1 (OC=128) + fused alpha1 ----------
__global__ __launch_bounds__(256) void mmt1_kernel(const float* __restrict__ X,
                                                   const unsigned short* __restrict__ Wb,
                                                   const float* __restrict__ asv, const float* __restrict__ adv,
                                                   unsigned short* __restrict__ outb,
                                                   float* __restrict__ as1, float* __restrict__ ad1){
  constexpr int OC = 128, CT = 8;
  int t = threadIdx.x;
  int w = t >> 6, L = t & 63;
  int col = L & 15, quad = L >> 4;
  int row0 = blockIdx.x*64 + w*16;
  int rA = row0 + col;
  if(rA >= N_NODES) rA = N_NODES-1;

  f32x4 acc[CT];
  #pragma unroll
  for(int ct=0;ct<CT;ct++) acc[ct] = (f32x4){0.f,0.f,0.f,0.f};

  #pragma unroll
  for(int kc=0;kc<4;kc++){
    int k0 = kc*32 + quad*8;
    const float* Xf = X + (size_t)rA*KD + k0;
    float4 p = *(const float4*)Xf;
    float4 q = *(const float4*)(Xf + 4);
    bf16x8 a;
    a[0] = (short)f2bf(p.x); a[1] = (short)f2bf(p.y);
    a[2] = (short)f2bf(p.z); a[3] = (short)f2bf(p.w);
    a[4] = (short)f2bf(q.x); a[5] = (short)f2bf(q.y);
    a[6] = (short)f2bf(q.z); a[7] = (short)f2bf(q.w);
    #pragma unroll
    for(int ct=0;ct<CT;ct++){
      bf16x8 b = *(const bf16x8*)(Wb + (size_t)(ct*16 + col)*KD + k0);
      acc[ct] = __builtin_amdgcn_mfma_f32_16x16x32_bf16(a, b, acc[ct], 0, 0, 0);
    }
  }

  float av[CT], dv[CT];
  #pragma unroll
  for(int ct=0;ct<CT;ct++){ av[ct] = asv[ct*16 + col]; dv[ct] = adv[ct*16 + col]; }

  #pragma unroll
  for(int r=0;r<4;r++){
    int row = row0 + quad*4 + r;
    #pragma unroll
    for(int ct=0;ct<CT;ct++)
      if(row < N_NODES) outb[(size_t)row*OC + ct*16 + col] = f2bf(acc[ct][r]);
    float s0 = acc[0][r]*av[0] + acc[1][r]*av[1] + acc[2][r]*av[2] + acc[3][r]*av[3];
    float s1 = acc[4][r]*av[4] + acc[5][r]*av[5] + acc[6][r]*av[6] + acc[7][r]*av[7];
    float d0 = acc[0][r]*dv[0] + acc[1][r]*dv[1] + acc[2][r]*dv[2] + acc[3][r]*dv[3];
    float d1 = acc[4][r]*dv[4] + acc[5][r]*dv[5] + acc[6][r]*dv[6] + acc[7][r]*dv[7];
    #pragma unroll
    for(int off=1; off<16; off<<=1){
      s0 += __shfl_xor(s0, off); s1 += __shfl_xor(s1, off);
      d0 += __shfl_xor(d0, off); d1 += __shfl_xor(d1, off);
    }
    if(col == 0 && row < N_NODES){
      as1[row*2] = s0; as1[row*2+1] = s1;
      ad1[row*2] = d0; ad1[row*2+1] = d1;
    }
  }
}

// ---------- MFMA matmul layer2 (OC=64, bf16 X) + fused alpha2 ----------
__global__ __launch_bounds__(256) void mmt2_kernel(const unsigned short* __restrict__ Xb,
                                                   const unsigned short* __restrict__ Wb,
                                                   const float* __restrict__ asmu, const float* __restrict__ admu,
                                                   const float* __restrict__ asst, const float* __restrict__ adst,
                                                   unsigned short* __restrict__ outb,
                                                   float* __restrict__ as2, float* __restrict__ ad2){
  constexpr int OC = 64, CT = 4;
  int t = threadIdx.x;
  int w = t >> 6, L = t & 63;
  int col = L & 15, quad = L >> 4;
  int row0 = blockIdx.x*64 + w*16;
  int rA = row0 + col;
  if(rA >= N_NODES) rA = N_NODES-1;

  f32x4 acc[CT];
  #pragma unroll
  for(int ct=0;ct<CT;ct++) acc[ct] = (f32x4){0.f,0.f,0.f,0.f};

  #pragma unroll
  for(int kc=0;kc<4;kc++){
    int k0 = kc*32 + quad*8;
    bf16x8 a = *(const bf16x8*)(Xb + (size_t)rA*KD + k0);
    #pragma unroll
    for(int ct=0;ct<CT;ct++){
      bf16x8 b = *(const bf16x8*)(Wb + (size_t)(ct*16 + col)*KD + k0);
      acc[ct] = __builtin_amdgcn_mfma_f32_16x16x32_bf16(a, b, acc[ct], 0, 0, 0);
    }
  }

  float av[CT], dv[CT];
  #pragma unroll
  for(int ct=0;ct<CT;ct++){
    av[ct] = (ct < 2) ? asmu[ct*16 + col] : asst[(ct-2)*16 + col];
    dv[ct] = (ct < 2) ? admu[ct*16 + col] : adst[(ct-2)*16 + col];
  }

  #pragma unroll
  for(int r=0;r<4;r++){
    int row = row0 + quad*4 + r;
    #pragma unroll
    for(int ct=0;ct<CT;ct++)
      if(row < N_NODES) outb[(size_t)row*OC + ct*16 + col] = f2bf(acc[ct][r]);
    float smu = acc[0][r]*av[0] + acc[1][r]*av[1];
    float sst = acc[2][r]*av[2] + acc[3][r]*av[3];
    float dmu = acc[0][r]*dv[0] + acc[1][r]*dv[1];
    float dst = acc[2][r]*dv[2] + acc[3][r]*dv[3];
    #pragma unroll
    for(int off=1; off<16; off<<=1){
      smu += __shfl_xor(smu, off); sst += __shfl_xor(sst, off);
      dmu += __shfl_xor(dmu, off); dst += __shfl_xor(dst, off);
    }
    if(col == 0 && row < N_NODES){
      as2[row*2] = smu; as2[row*2+1] = sst;
      ad2[row*2] = dmu; ad2[row*2+1] = dst;
    }
  }
}

// ---------- edge-parallel softmax-weight precompute ----------
__global__ __launch_bounds__(256) void wcalc_kernel(const int* __restrict__ esrc, const int* __restrict__ edst,
                                                    const float* __restrict__ as, const float* __restrict__ ad,
                                                    float2* __restrict__ wp){
  int i = blockIdx.x*256 + threadIdx.x;
  if(i >= ET) return;
  int s = esrc[i], d = edst[i];
  float2 a = ((const float2*)as)[s];
  float2 b = ((const float2*)ad)[d];
  wp[i] = make_float2(__expf(lrelu(a.x + b.x)), __expf(lrelu(a.y + b.y)));
}

// ---------- agg layer 1: pipelined index prefetch + masked epilogue ----------
// esrc/wp are padded (+32) so all loads are unconditional; pad esrc entries are 0.
__global__ __launch_bounds__(256) void agg1_kernel(const int* __restrict__ rowptr, const int* __restrict__ esrc,
                                                   const float2* __restrict__ wp,
                                                   const unsigned int* __restrict__ xb,
                                                   const float* __restrict__ b1, unsigned int* __restrict__ hb){
  int node = blockIdx.x*4 + (threadIdx.x>>6);
  int l = threadIdx.x & 63;
  if(node >= N_NODES) return;
  int beg = rowptr[node], end = rowptr[node+1];
  int n = end - beg;
  float accx = 0.f, accy = 0.f, s0 = 0.f, s1 = 0.f;

  int e_n[8];
  #pragma unroll
  for(int j=0;j<8;j++) e_n[j] = esrc[beg+j];          // prologue prefetch (padded)

  int nfull = n & ~7;
  int i = beg;
  for(; i < beg + nfull; i += 8){
    int e_c[8];
    #pragma unroll
    for(int j=0;j<8;j++) e_c[j] = e_n[j];
    unsigned int u[8];
    #pragma unroll
    for(int j=0;j<8;j++) u[j] = xb[(size_t)e_c[j]*64 + l];   // gathers (dep on prefetched idx)
    #pragma unroll
    for(int j=0;j<8;j++) e_n[j] = esrc[i+8+j];               // prefetch next iter's idx
    float2 w[8];
    #pragma unroll
    for(int j=0;j<8;j++) w[j] = wp[i+j];                     // position-indexed, independent
    #pragma unroll
    for(int j=0;j<8;j++){
      s0 += w[j].x; s1 += w[j].y;
      float vv = (l < 32) ? w[j].x : w[j].y;
      accx += vv * lof(u[j]); accy += vv * hif(u[j]);
    }
  }
  if(i < end){                                               // masked epilogue, no serial tail
    unsigned int u[8];
    #pragma unroll
    for(int j=0;j<8;j++) u[j] = xb[(size_t)e_n[j]*64 + l];
    float2 w[8];
    #pragma unroll
    for(int j=0;j<8;j++) w[j] = wp[i+j];
    #pragma unroll
    for(int j=0;j<8;j++){
      float wx = (i+j < end) ? w[j].x : 0.f;
      float wy = (i+j < end) ? w[j].y : 0.f;
      s0 += wx; s1 += wy;
      float vv = (l < 32) ? wx : wy;
      accx += vv * lof(u[j]); accy += vv * hif(u[j]);
    }
  }
  float sd = (l < 32) ? s0 : s1;
  float2 bb = ((const float2*)b1)[l];
  float rx = fmaxf(accx/sd + bb.x, 0.f);
  float ry = fmaxf(accy/sd + bb.y, 0.f);
  unsigned int hp = (unsigned int)f2bf(rx) | ((unsigned int)f2bf(ry) << 16);
  hb[(size_t)node*64 + l] = hp;
}

// ---------- agg layer 2: 4 edges/instr, pipelined prefetch + masked epilogue ----------
__global__ __launch_bounds__(256) void agg2_kernel(const int* __restrict__ rowptr, const int* __restrict__ esrc,
                                                   const float2* __restrict__ wp,
                                                   const uint2* __restrict__ xb2,
                                                   const float* __restrict__ bmu, const float* __restrict__ bst,
                                                   float* __restrict__ out){
  int node = blockIdx.x*4 + (threadIdx.x>>6);
  int l = threadIdx.x & 63;
  if(node >= N_NODES) return;
  int g = l >> 4, c = l & 15;        // group g handles edges i0+g, i0+4+g, i0+8+g, i0+12+g
  int beg = rowptr[node], end = rowptr[node+1];
  int n = end - beg;
  float a0=0.f, a1=0.f, a2=0.f, a3=0.f, smu=0.f, sst=0.f;

  int e_n[4];
  #pragma unroll
  for(int j=0;j<4;j++) e_n[j] = esrc[beg + g + 4*j];

  int nfull = n & ~15;
  int i0 = beg;
  for(; i0 < beg + nfull; i0 += 16){
    int e_c[4];
    #pragma unroll
    for(int j=0;j<4;j++) e_c[j] = e_n[j];
    uint2 u[4];
    #pragma unroll
    for(int j=0;j<4;j++) u[j] = xb2[(size_t)e_c[j]*16 + c];
    #pragma unroll
    for(int j=0;j<4;j++) e_n[j] = esrc[i0 + 16 + g + 4*j];
    float2 w[4];
    #pragma unroll
    for(int j=0;j<4;j++) w[j] = wp[i0 + g + 4*j];
    #pragma unroll
    for(int j=0;j<4;j++){
      smu += w[j].x; sst += w[j].y;
      float vv = (c < 8) ? w[j].x : w[j].y;
      a0 += vv*lof(u[j].x); a1 += vv*hif(u[j].x);
      a2 += vv*lof(u[j].y); a3 += vv*hif(u[j].y);
    }
  }
  if(i0 < end){
    uint2 u[4];
    #pragma unroll
    for(int j=0;j<4;j++) u[j] = xb2[(size_t)e_n[j]*16 + c];
    float2 w[4];
    #pragma unroll
    for(int j=0;j<4;j++) w[j] = wp[i0 + g + 4*j];
    #pragma unroll
    for(int j=0;j<4;j++){
      int idx = i0 + g + 4*j;
      float wx = (idx < end) ? w[j].x : 0.f;
      float wy = (idx < end) ? w[j].y : 0.f;
      smu += wx; sst += wy;
      float vv = (c < 8) ? wx : wy;
      a0 += vv*lof(u[j].x); a1 += vv*hif(u[j].x);
      a2 += vv*lof(u[j].y); a3 += vv*hif(u[j].y);
    }
  }
  #pragma unroll
  for(int off = 16; off < 64; off <<= 1){
    smu += __shfl_xor(smu, off); sst += __shfl_xor(sst, off);
    a0 += __shfl_xor(a0, off); a1 += __shfl_xor(a1, off);
    a2 += __shfl_xor(a2, off); a3 += __shfl_xor(a3, off);
  }
  float sd = (c < 8) ? smu : sst;
  float4 bb = (c < 8) ? *(const float4*)(bmu + 4*c) : *(const float4*)(bst + 4*(c-8));
  float4 r;
  r.x = a0/sd + bb.x;
  r.y = a1/sd + bb.y;
  r.z = a2/sd + bb.z;
  r.w = a3/sd + bb.w;
  if(g == 0){
    float* dst = (c < 8) ? (out + (size_t)node*Z + 4*c)
                         : (out + (size_t)N_NODES*Z + (size_t)node*Z + 4*(c-8));
    *(float4*)dst = r;
  }
}

extern "C" void kernel_launch(void* const* d_in, const int* in_sizes, int n_in,
                              void* d_out, int out_size, void* d_ws, size_t ws_size,
                              hipStream_t stream){
  const float* x    = (const float*)d_in[0];
  const int*   edges= (const int*)d_in[1];
  const float* W1   = (const float*)d_in[2];
  const float* as1v = (const float*)d_in[3];
  const float* ad1v = (const float*)d_in[4];
  const float* b1   = (const float*)d_in[5];
  const float* Wmu  = (const float*)d_in[6];
  const float* asmu = (const float*)d_in[7];
  const float* admu = (const float*)d_in[8];
  const float* bmu  = (const float*)d_in[9];
  const float* Wst  = (const float*)d_in[10];
  const float* asst = (const float*)d_in[11];
  const float* adst = (const float*)d_in[12];
  const float* bst  = (const float*)d_in[13];
  float* out = (float*)d_out;

  char* p = (char*)d_ws;
  auto alloc = [&](size_t bytes)->char*{ char* r = p; p += (bytes + 255) & ~size_t(255); return r; };
  int*   M      = (int*)  alloc((size_t)MTOT*4);
  int*   Mpos   = (int*)  alloc((size_t)MTOT*4);
  int*   bsumM  = (int*)  alloc((size_t)MBS*4);
  int*   bpreM  = (int*)  alloc((size_t)MBS*4);
  int2*  etmp   = (int2*) alloc((size_t)(ET+32)*8);   // also reused as padded wp
  int*   esrc   = (int*)  alloc((size_t)(ET+32)*4);   // +32 zeroed pad for unconditional loads
  int*   edst   = (int*)  alloc((size_t)ET*4);
  int*   rowptr = (int*)  alloc((size_t)(N_NODES+1)*4);
  unsigned short* Wb1 = (unsigned short*)alloc((size_t)128*KD*2);
  unsigned short* Wb2 = (unsigned short*)alloc((size_t)64*KD*2);
  unsigned short* xpb1 = (unsigned short*)alloc((size_t)N_NODES*128*2);
  float* as1    = (float*)alloc((size_t)N_NODES*2*4);
  float* ad1    = (float*)alloc((size_t)N_NODES*2*4);
  unsigned short* hb = (unsigned short*)alloc((size_t)N_NODES*128*2);
  float* as2    = (float*)alloc((size_t)N_NODES*2*4);
  float* ad2    = (float*)alloc((size_t)N_NODES*2*4);
  unsigned short* xpb2 = xpb1;                          // xpb1 dead after agg1
  float2* wedge = (float2*)etmp;                        // etmp dead after bfin

  bhistA_kernel  <<<NBLKA, 256, 0, stream>>>(edges, M);
  scanM1_kernel  <<<MBS, 256, 0, stream>>>(M, bsumM);
  scanM2_kernel  <<<1, 256, 0, stream>>>(bsumM, bpreM);
  scanM3_kernel  <<<MBS, 256, 0, stream>>>(M, bpreM, Mpos);
  bplaceA_kernel <<<NBLKA, 256, 0, stream>>>(edges, Mpos, etmp);
  bfin_kernel    <<<NBUCK, 256, 0, stream>>>(Mpos, etmp, rowptr, esrc, edst);

  wconv_kernel   <<<(128*KD + 255)/256, 256, 0, stream>>>(W1, Wmu, Wst, Wb1, Wb2);

  mmt1_kernel  <<<(N_NODES+63)/64, 256, 0, stream>>>(x, Wb1, as1v, ad1v, xpb1, as1, ad1);
  wcalc_kernel <<<(ET+255)/256, 256, 0, stream>>>(esrc, edst, as1, ad1, wedge);
  agg1_kernel  <<<(N_NODES+3)/4, 256, 0, stream>>>(rowptr, esrc, wedge, (const unsigned int*)xpb1, b1, (unsigned int*)hb);

  mmt2_kernel  <<<(N_NODES+63)/64, 256, 0, stream>>>(hb, Wb2, asmu, admu, asst, adst, xpb1, as2, ad2);
  wcalc_kernel <<<(ET+255)/256, 256, 0, stream>>>(esrc, edst, as2, ad2, wedge);
  agg2_kernel  <<<(N_NODES+3)/4, 256, 0, stream>>>(rowptr, esrc, wedge, (const uint2*)xpb2, bmu, bst, out);
}

// Round 3
// 238.826 us; speedup vs baseline: 1.0588x; 1.0474x over previous
//
#include <hip/hip_runtime.h>
#include <math.h>

#define N_NODES 50000
#define N_EDGES 800000
#define ET (N_EDGES + N_NODES)   // 850000 incl. self-loops
#define KD 128
#define Z 32
#define SH 7
#define BW 128                              // nodes per bucket
#define NBUCK ((N_NODES + BW - 1) / BW)     // 391
#define CHUNK 4096
#define NBLKA ((ET + CHUNK - 1) / CHUNK)    // 208 chunks
#define MTOT (NBUCK * NBLKA)                // 81,328
#define MBS ((MTOT + 1023) / 1024)          // 80

typedef __attribute__((ext_vector_type(8))) short bf16x8;
typedef __attribute__((ext_vector_type(4))) float f32x4;

static __device__ __forceinline__ float lrelu(float x){ return x > 0.f ? x : 0.2f*x; }
static __device__ __forceinline__ float lof(unsigned int u){ return __uint_as_float(u << 16); }
static __device__ __forceinline__ float hif(unsigned int u){ return __uint_as_float(u & 0xffff0000u); }
static __device__ __forceinline__ unsigned short f2bf(float f){
  unsigned int x = __float_as_uint(f);
  return (unsigned short)((x + 0x7fffu + ((x >> 16) & 1u)) >> 16);   // RNE
}
static __device__ __forceinline__ unsigned int pack2(float lo, float hi){
  return (unsigned int)f2bf(lo) | ((unsigned int)f2bf(hi) << 16);
}

// ---------- CSR build: counting sort, NO global atomics ----------
__global__ __launch_bounds__(256) void bhistA_kernel(const int* __restrict__ edges, int* __restrict__ M){
  int k = blockIdx.x, t = threadIdx.x;
  __shared__ int cnt[NBUCK];
  for(int b = t; b < NBUCK; b += 256) cnt[b] = 0;
  __syncthreads();
  int base = k*CHUNK;
  int lim = min(base + CHUNK, ET);
  for(int i = base + t; i < lim; i += 256){
    int d = (i < N_EDGES) ? edges[N_EDGES + i] : (i - N_EDGES);
    atomicAdd(&cnt[d >> SH], 1);
  }
  __syncthreads();
  for(int b = t; b < NBUCK; b += 256) M[b*NBLKA + k] = cnt[b];
}

__global__ __launch_bounds__(256) void scanM1_kernel(const int* __restrict__ M, int* __restrict__ bsumM){
  int b = blockIdx.x, t = threadIdx.x;
  int base = b*1024 + t*4;
  int s = 0;
  #pragma unroll
  for(int i=0;i<4;i++){ int n = base+i; if(n < MTOT) s += M[n]; }
  for(int off=32; off; off>>=1) s += __shfl_xor(s, off);
  __shared__ int ws[4];
  if((t&63)==0) ws[t>>6] = s;
  __syncthreads();
  if(t==0) bsumM[b] = ws[0]+ws[1]+ws[2]+ws[3];
}

__global__ __launch_bounds__(256) void scanM2_kernel(const int* __restrict__ bsumM, int* __restrict__ bpreM){
  __shared__ int sm[256];
  int t = threadIdx.x;
  int v = (t < MBS) ? bsumM[t] : 0;
  sm[t] = v;
  __syncthreads();
  for(int off=1; off<256; off<<=1){
    int u = (t >= off) ? sm[t-off] : 0;
    __syncthreads();
    sm[t] += u;
    __syncthreads();
  }
  if(t < MBS) bpreM[t] = sm[t] - v;
}

__global__ __launch_bounds__(256) void scanM3_kernel(const int* __restrict__ M, const int* __restrict__ bpreM,
                                                     int* __restrict__ Mpos){
  int b = blockIdx.x, t = threadIdx.x;
  int lane = t & 63, wv = t >> 6;
  int base = b*1024 + t*4;
  int d[4]; int s = 0;
  #pragma unroll
  for(int i=0;i<4;i++){ int n = base+i; d[i] = (n < MTOT) ? M[n] : 0; s += d[i]; }
  int v = s;
  for(int off=1; off<64; off<<=1){
    int u = __shfl_up(v, off);
    if(lane >= off) v += u;
  }
  int texcl = v - s;
  __shared__ int wtot[4];
  if(lane == 63) wtot[wv] = v;
  __syncthreads();
  int woff = 0;
  for(int i=0;i<wv;i++) woff += wtot[i];
  int run = bpreM[b] + woff + texcl;
  #pragma unroll
  for(int i=0;i<4;i++){
    int n = base+i;
    if(n < MTOT){ Mpos[n] = run; run += d[i]; }
  }
}

__global__ __launch_bounds__(256) void bplaceA_kernel(const int* __restrict__ edges, const int* __restrict__ Mpos,
                                                      int2* __restrict__ etmp){
  int k = blockIdx.x, t = threadIdx.x;
  __shared__ int cur[NBUCK];
  for(int b = t; b < NBUCK; b += 256) cur[b] = Mpos[b*NBLKA + k];
  __syncthreads();
  int base = k*CHUNK;
  int lim = min(base + CHUNK, ET);
  for(int i = base + t; i < lim; i += 256){
    int s, d;
    if(i < N_EDGES){ s = edges[i]; d = edges[N_EDGES+i]; } else { s = d = i - N_EDGES; }
    int pos = atomicAdd(&cur[d >> SH], 1);
    etmp[pos] = make_int2(s, d);
  }
}

// fused: per-bucket node histogram + local scan -> rowptr + in-bucket place -> esrc + edst
__global__ __launch_bounds__(256) void bfin_kernel(const int* __restrict__ Mpos, const int2* __restrict__ etmp,
                                                   int* __restrict__ rowptr, int* __restrict__ esrc,
                                                   int* __restrict__ edst){
  int b = blockIdx.x, t = threadIdx.x;
  __shared__ int cnt[BW];
  __shared__ int pre[BW];
  __shared__ int lcur[BW];
  if(t < BW) cnt[t] = 0;
  if(b == 0 && t < 32) esrc[ET + t] = 0;     // zero pad: agg kernels overread up to +16
  __syncthreads();
  int beg = Mpos[b*NBLKA];
  int end = (b+1 < NBUCK) ? Mpos[(b+1)*NBLKA] : ET;
  for(int i = beg + t; i < end; i += 256) atomicAdd(&cnt[etmp[i].y & (BW-1)], 1);
  __syncthreads();
  if(t < BW) pre[t] = cnt[t];
  __syncthreads();
  for(int off=1; off<BW; off<<=1){
    int u = 0;
    if(t < BW && t >= off) u = pre[t-off];
    __syncthreads();
    if(t < BW) pre[t] += u;
    __syncthreads();
  }
  if(t < BW){
    int excl = pre[t] - cnt[t];
    int node = b*BW + t;
    if(node < N_NODES) rowptr[node] = beg + excl;
    lcur[t] = beg + excl;
  }
  if(b == 0 && t == 255) rowptr[N_NODES] = ET;
  __syncthreads();
  for(int i = beg + t; i < end; i += 256){
    int2 e = etmp[i];
    int pos = atomicAdd(&lcur[e.y & (BW-1)], 1);
    esrc[pos] = e.x;
    edst[pos] = e.y;
  }
}

// ---------- W -> bf16 converter ----------
__global__ __launch_bounds__(256) void wconv_kernel(const float* __restrict__ W1,
                                                    const float* __restrict__ Wmu, const float* __restrict__ Wst,
                                                    unsigned short* __restrict__ Wb1, unsigned short* __restrict__ Wb2){
  int i = blockIdx.x*256 + threadIdx.x;
  if(i < 128*KD) Wb1[i] = f2bf(W1[i]);
  if(i < 64*KD) Wb2[i] = f2bf(i < 32*KD ? Wmu[i] : Wst[i - 32*KD]);
}

// ---------- MFMA matmul layer1 (OC=128) + fused alpha1 ----------
__global__ __launch_bounds__(256) void mmt1_kernel(const float* __restrict__ X,
                                                   const unsigned short* __restrict__ Wb,
                                                   const float* __restrict__ asv, const float* __restrict__ adv,
                                                   unsigned short* __restrict__ outb,
                                                   float* __restrict__ as1, float* __restrict__ ad1){
  constexpr int OC = 128, CT = 8;
  int t = threadIdx.x;
  int w = t >> 6, L = t & 63;
  int col = L & 15, quad = L >> 4;
  int row0 = blockIdx.x*64 + w*16;
  int rA = row0 + col;
  if(rA >= N_NODES) rA = N_NODES-1;

  f32x4 acc[CT];
  #pragma unroll
  for(int ct=0;ct<CT;ct++) acc[ct] = (f32x4){0.f,0.f,0.f,0.f};

  #pragma unroll
  for(int kc=0;kc<4;kc++){
    int k0 = kc*32 + quad*8;
    const float* Xf = X + (size_t)rA*KD + k0;
    float4 p = *(const float4*)Xf;
    float4 q = *(const float4*)(Xf + 4);
    bf16x8 a;
    a[0] = (short)f2bf(p.x); a[1] = (short)f2bf(p.y);
    a[2] = (short)f2bf(p.z); a[3] = (short)f2bf(p.w);
    a[4] = (short)f2bf(q.x); a[5] = (short)f2bf(q.y);
    a[6] = (short)f2bf(q.z); a[7] = (short)f2bf(q.w);
    #pragma unroll
    for(int ct=0;ct<CT;ct++){
      bf16x8 b = *(const bf16x8*)(Wb + (size_t)(ct*16 + col)*KD + k0);
      acc[ct] = __builtin_amdgcn_mfma_f32_16x16x32_bf16(a, b, acc[ct], 0, 0, 0);
    }
  }

  float av[CT], dv[CT];
  #pragma unroll
  for(int ct=0;ct<CT;ct++){ av[ct] = asv[ct*16 + col]; dv[ct] = adv[ct*16 + col]; }

  #pragma unroll
  for(int r=0;r<4;r++){
    int row = row0 + quad*4 + r;
    #pragma unroll
    for(int ct=0;ct<CT;ct++)
      if(row < N_NODES) outb[(size_t)row*OC + ct*16 + col] = f2bf(acc[ct][r]);
    float s0 = acc[0][r]*av[0] + acc[1][r]*av[1] + acc[2][r]*av[2] + acc[3][r]*av[3];
    float s1 = acc[4][r]*av[4] + acc[5][r]*av[5] + acc[6][r]*av[6] + acc[7][r]*av[7];
    float d0 = acc[0][r]*dv[0] + acc[1][r]*dv[1] + acc[2][r]*dv[2] + acc[3][r]*dv[3];
    float d1 = acc[4][r]*dv[4] + acc[5][r]*dv[5] + acc[6][r]*dv[6] + acc[7][r]*dv[7];
    #pragma unroll
    for(int off=1; off<16; off<<=1){
      s0 += __shfl_xor(s0, off); s1 += __shfl_xor(s1, off);
      d0 += __shfl_xor(d0, off); d1 += __shfl_xor(d1, off);
    }
    if(col == 0 && row < N_NODES){
      as1[row*2] = s0; as1[row*2+1] = s1;
      ad1[row*2] = d0; ad1[row*2+1] = d1;
    }
  }
}

// ---------- MFMA matmul layer2 (OC=64, bf16 X) + fused alpha2 ----------
__global__ __launch_bounds__(256) void mmt2_kernel(const unsigned short* __restrict__ Xb,
                                                   const unsigned short* __restrict__ Wb,
                                                   const float* __restrict__ asmu, const float* __restrict__ admu,
                                                   const float* __restrict__ asst, const float* __restrict__ adst,
                                                   unsigned short* __restrict__ outb,
                                                   float* __restrict__ as2, float* __restrict__ ad2){
  constexpr int OC = 64, CT = 4;
  int t = threadIdx.x;
  int w = t >> 6, L = t & 63;
  int col = L & 15, quad = L >> 4;
  int row0 = blockIdx.x*64 + w*16;
  int rA = row0 + col;
  if(rA >= N_NODES) rA = N_NODES-1;

  f32x4 acc[CT];
  #pragma unroll
  for(int ct=0;ct<CT;ct++) acc[ct] = (f32x4){0.f,0.f,0.f,0.f};

  #pragma unroll
  for(int kc=0;kc<4;kc++){
    int k0 = kc*32 + quad*8;
    bf16x8 a = *(const bf16x8*)(Xb + (size_t)rA*KD + k0);
    #pragma unroll
    for(int ct=0;ct<CT;ct++){
      bf16x8 b = *(const bf16x8*)(Wb + (size_t)(ct*16 + col)*KD + k0);
      acc[ct] = __builtin_amdgcn_mfma_f32_16x16x32_bf16(a, b, acc[ct], 0, 0, 0);
    }
  }

  float av[CT], dv[CT];
  #pragma unroll
  for(int ct=0;ct<CT;ct++){
    av[ct] = (ct < 2) ? asmu[ct*16 + col] : asst[(ct-2)*16 + col];
    dv[ct] = (ct < 2) ? admu[ct*16 + col] : adst[(ct-2)*16 + col];
  }

  #pragma unroll
  for(int r=0;r<4;r++){
    int row = row0 + quad*4 + r;
    #pragma unroll
    for(int ct=0;ct<CT;ct++)
      if(row < N_NODES) outb[(size_t)row*OC + ct*16 + col] = f2bf(acc[ct][r]);
    float smu = acc[0][r]*av[0] + acc[1][r]*av[1];
    float sst = acc[2][r]*av[2] + acc[3][r]*av[3];
    float dmu = acc[0][r]*dv[0] + acc[1][r]*dv[1];
    float dst = acc[2][r]*dv[2] + acc[3][r]*dv[3];
    #pragma unroll
    for(int off=1; off<16; off<<=1){
      smu += __shfl_xor(smu, off); sst += __shfl_xor(sst, off);
      dmu += __shfl_xor(dmu, off); dst += __shfl_xor(dst, off);
    }
    if(col == 0 && row < N_NODES){
      as2[row*2] = smu; as2[row*2+1] = sst;
      ad2[row*2] = dmu; ad2[row*2+1] = dst;
    }
  }
}

// ---------- edge-parallel softmax-weight precompute ----------
__global__ __launch_bounds__(256) void wcalc_kernel(const int* __restrict__ esrc, const int* __restrict__ edst,
                                                    const float* __restrict__ as, const float* __restrict__ ad,
                                                    float2* __restrict__ wp){
  int i = blockIdx.x*256 + threadIdx.x;
  if(i >= ET) return;
  int s = esrc[i], d = edst[i];
  float2 a = ((const float2*)as)[s];
  float2 b = ((const float2*)ad)[d];
  wp[i] = make_float2(__expf(lrelu(a.x + b.x)), __expf(lrelu(a.y + b.y)));
}

// ---------- agg layer 1: 4 edges/step, uint4 row gathers (16 lanes x 16B = 256B row) ----------
// row = 128 bf16 = 64 uints = 16 uint4. group g (of 4) handles edge i+g; lane c covers uints 4c..4c+3.
// head0 = uints 0..31 (c<8), head1 = uints 32..63 (c>=8).
__global__ __launch_bounds__(256) void agg1_kernel(const int* __restrict__ rowptr, const int* __restrict__ esrc,
                                                   const float2* __restrict__ wp,
                                                   const uint4* __restrict__ xb4,
                                                   const float* __restrict__ b1, uint4* __restrict__ hb4){
  int node = blockIdx.x*4 + (threadIdx.x>>6);
  int l = threadIdx.x & 63;
  if(node >= N_NODES) return;
  int g = l >> 4, c = l & 15;
  int beg = rowptr[node], end = rowptr[node+1];
  int n = end - beg;
  float a0=0.f,a1=0.f,a2=0.f,a3=0.f,a4=0.f,a5=0.f,a6=0.f,a7=0.f;
  float s0=0.f, s1=0.f;

#define S1_STEP(IDX) { \
    int e_ = esrc[(IDX)]; \
    float2 w_ = wp[(IDX)]; \
    uint4 u_ = xb4[(size_t)e_*16 + c]; \
    s0 += w_.x; s1 += w_.y; \
    float vv = (c < 8) ? w_.x : w_.y; \
    a0 += vv*lof(u_.x); a1 += vv*hif(u_.x); \
    a2 += vv*lof(u_.y); a3 += vv*hif(u_.y); \
    a4 += vv*lof(u_.z); a5 += vv*hif(u_.z); \
    a6 += vv*lof(u_.w); a7 += vv*hif(u_.w); }

#define S1_STEPM(IDX) { \
    int e_ = esrc[(IDX)]; \
    float2 w_ = wp[(IDX)]; \
    uint4 u_ = xb4[(size_t)e_*16 + c]; \
    float wx_ = ((IDX) < end) ? w_.x : 0.f; \
    float wy_ = ((IDX) < end) ? w_.y : 0.f; \
    s0 += wx_; s1 += wy_; \
    float vv = (c < 8) ? wx_ : wy_; \
    a0 += vv*lof(u_.x); a1 += vv*hif(u_.x); \
    a2 += vv*lof(u_.y); a3 += vv*hif(u_.y); \
    a4 += vv*lof(u_.z); a5 += vv*hif(u_.z); \
    a6 += vv*lof(u_.w); a7 += vv*hif(u_.w); }

  int i = beg;
  int nfull = n & ~7;
  for(; i < beg + nfull; i += 8){
    S1_STEP(i + g)
    S1_STEP(i + 4 + g)
  }
  if(i < end){               // masked epilogue: up to 7 real edges, pad gathers hit row 0 (L1-hot)
    S1_STEPM(i + g)
    S1_STEPM(i + 4 + g)
  }
#undef S1_STEP
#undef S1_STEPM

  #pragma unroll
  for(int off=16; off<64; off<<=1){
    s0 += __shfl_xor(s0,off); s1 += __shfl_xor(s1,off);
    a0 += __shfl_xor(a0,off); a1 += __shfl_xor(a1,off);
    a2 += __shfl_xor(a2,off); a3 += __shfl_xor(a3,off);
    a4 += __shfl_xor(a4,off); a5 += __shfl_xor(a5,off);
    a6 += __shfl_xor(a6,off); a7 += __shfl_xor(a7,off);
  }
  if(g == 0){
    float sd = (c < 8) ? s0 : s1;
    float inv = 1.f / sd;
    const float4* bp = (const float4*)(b1 + 8*c);
    float4 bl = bp[0], bh = bp[1];
    float r0 = fmaxf(a0*inv + bl.x, 0.f);
    float r1 = fmaxf(a1*inv + bl.y, 0.f);
    float r2 = fmaxf(a2*inv + bl.z, 0.f);
    float r3 = fmaxf(a3*inv + bl.w, 0.f);
    float r4 = fmaxf(a4*inv + bh.x, 0.f);
    float r5 = fmaxf(a5*inv + bh.y, 0.f);
    float r6 = fmaxf(a6*inv + bh.z, 0.f);
    float r7 = fmaxf(a7*inv + bh.w, 0.f);
    uint4 o;
    o.x = pack2(r0, r1); o.y = pack2(r2, r3);
    o.z = pack2(r4, r5); o.w = pack2(r6, r7);
    hb4[(size_t)node*16 + c] = o;
  }
}

// ---------- agg layer 2: 8 edges/step, uint4 row gathers (8 lanes x 16B = 128B row) ----------
// row = 64 bf16 = 32 uints = 8 uint4. group g (of 8) handles edge i+g; lane c covers uints 4c..4c+3.
// mu = uints 0..15 (c<4), std = uints 16..31 (c>=4).
__global__ __launch_bounds__(256) void agg2_kernel(const int* __restrict__ rowptr, const int* __restrict__ esrc,
                                                   const float2* __restrict__ wp,
                                                   const uint4* __restrict__ xb4,
                                                   const float* __restrict__ bmu, const float* __restrict__ bst,
                                                   float* __restrict__ out){
  int node = blockIdx.x*4 + (threadIdx.x>>6);
  int l = threadIdx.x & 63;
  if(node >= N_NODES) return;
  int g = l >> 3, c = l & 7;
  int beg = rowptr[node], end = rowptr[node+1];
  int n = end - beg;
  float a0=0.f,a1=0.f,a2=0.f,a3=0.f,a4=0.f,a5=0.f,a6=0.f,a7=0.f;
  float smu=0.f, sst=0.f;

#define S2_STEP(IDX) { \
    int e_ = esrc[(IDX)]; \
    float2 w_ = wp[(IDX)]; \
    uint4 u_ = xb4[(size_t)e_*8 + c]; \
    smu += w_.x; sst += w_.y; \
    float vv = (c < 4) ? w_.x : w_.y; \
    a0 += vv*lof(u_.x); a1 += vv*hif(u_.x); \
    a2 += vv*lof(u_.y); a3 += vv*hif(u_.y); \
    a4 += vv*lof(u_.z); a5 += vv*hif(u_.z); \
    a6 += vv*lof(u_.w); a7 += vv*hif(u_.w); }

#define S2_STEPM(IDX) { \
    int e_ = esrc[(IDX)]; \
    float2 w_ = wp[(IDX)]; \
    uint4 u_ = xb4[(size_t)e_*8 + c]; \
    float wx_ = ((IDX) < end) ? w_.x : 0.f; \
    float wy_ = ((IDX) < end) ? w_.y : 0.f; \
    smu += wx_; sst += wy_; \
    float vv = (c < 4) ? wx_ : wy_; \
    a0 += vv*lof(u_.x); a1 += vv*hif(u_.x); \
    a2 += vv*lof(u_.y); a3 += vv*hif(u_.y); \
    a4 += vv*lof(u_.z); a5 += vv*hif(u_.z); \
    a6 += vv*lof(u_.w); a7 += vv*hif(u_.w); }

  int i = beg;
  int nfull = n & ~15;
  for(; i < beg + nfull; i += 16){
    S2_STEP(i + g)
    S2_STEP(i + 8 + g)
  }
  if(i < end){               // masked epilogue: up to 15 real edges (2 masked steps)
    S2_STEPM(i + g)
    S2_STEPM(i + 8 + g)
  }
#undef S2_STEP
#undef S2_STEPM

  #pragma unroll
  for(int off=8; off<64; off<<=1){
    smu += __shfl_xor(smu,off); sst += __shfl_xor(sst,off);
    a0 += __shfl_xor(a0,off); a1 += __shfl_xor(a1,off);
    a2 += __shfl_xor(a2,off); a3 += __shfl_xor(a3,off);
    a4 += __shfl_xor(a4,off); a5 += __shfl_xor(a5,off);
    a6 += __shfl_xor(a6,off); a7 += __shfl_xor(a7,off);
  }
  if(g == 0){
    float sd = (c < 4) ? smu : sst;
    float inv = 1.f / sd;
    const float* bb = (c < 4) ? (bmu + 8*c) : (bst + 8*(c-4));
    float4 bl = *(const float4*)bb;
    float4 bh = *(const float4*)(bb + 4);
    float* op = (c < 4) ? (out + (size_t)node*Z + 8*c)
                        : (out + (size_t)N_NODES*Z + (size_t)node*Z + 8*(c-4));
    float4 r0, r1;
    r0.x = a0*inv + bl.x; r0.y = a1*inv + bl.y;
    r0.z = a2*inv + bl.z; r0.w = a3*inv + bl.w;
    r1.x = a4*inv + bh.x; r1.y = a5*inv + bh.y;
    r1.z = a6*inv + bh.z; r1.w = a7*inv + bh.w;
    *(float4*)op = r0;
    *((float4*)op + 1) = r1;
  }
}

extern "C" void kernel_launch(void* const* d_in, const int* in_sizes, int n_in,
                              void* d_out, int out_size, void* d_ws, size_t ws_size,
                              hipStream_t stream){
  const float* x    = (const float*)d_in[0];
  const int*   edges= (const int*)d_in[1];
  const float* W1   = (const float*)d_in[2];
  const float* as1v = (const float*)d_in[3];
  const float* ad1v = (const float*)d_in[4];
  const float* b1   = (const float*)d_in[5];
  const float* Wmu  = (const float*)d_in[6];
  const float* asmu = (const float*)d_in[7];
  const float* admu = (const float*)d_in[8];
  const float* bmu  = (const float*)d_in[9];
  const float* Wst  = (const float*)d_in[10];
  const float* asst = (const float*)d_in[11];
  const float* adst = (const float*)d_in[12];
  const float* bst  = (const float*)d_in[13];
  float* out = (float*)d_out;

  char* p = (char*)d_ws;
  auto alloc = [&](size_t bytes)->char*{ char* r = p; p += (bytes + 255) & ~size_t(255); return r; };
  int*   M      = (int*)  alloc((size_t)MTOT*4);
  int*   Mpos   = (int*)  alloc((size_t)MTOT*4);
  int*   bsumM  = (int*)  alloc((size_t)MBS*4);
  int*   bpreM  = (int*)  alloc((size_t)MBS*4);
  int2*  etmp   = (int2*) alloc((size_t)(ET+32)*8);   // also reused as padded wp
  int*   esrc   = (int*)  alloc((size_t)(ET+32)*4);   // +32 zeroed pad for unconditional loads
  int*   edst   = (int*)  alloc((size_t)ET*4);
  int*   rowptr = (int*)  alloc((size_t)(N_NODES+1)*4);
  unsigned short* Wb1 = (unsigned short*)alloc((size_t)128*KD*2);
  unsigned short* Wb2 = (unsigned short*)alloc((size_t)64*KD*2);
  unsigned short* xpb1 = (unsigned short*)alloc((size_t)N_NODES*128*2);
  float* as1    = (float*)alloc((size_t)N_NODES*2*4);
  float* ad1    = (float*)alloc((size_t)N_NODES*2*4);
  unsigned short* hb = (unsigned short*)alloc((size_t)N_NODES*128*2);
  float* as2    = (float*)alloc((size_t)N_NODES*2*4);
  float* ad2    = (float*)alloc((size_t)N_NODES*2*4);
  unsigned short* xpb2 = xpb1;                          // xpb1 dead after agg1
  float2* wedge = (float2*)etmp;                        // etmp dead after bfin

  bhistA_kernel  <<<NBLKA, 256, 0, stream>>>(edges, M);
  scanM1_kernel  <<<MBS, 256, 0, stream>>>(M, bsumM);
  scanM2_kernel  <<<1, 256, 0, stream>>>(bsumM, bpreM);
  scanM3_kernel  <<<MBS, 256, 0, stream>>>(M, bpreM, Mpos);
  bplaceA_kernel <<<NBLKA, 256, 0, stream>>>(edges, Mpos, etmp);
  bfin_kernel    <<<NBUCK, 256, 0, stream>>>(Mpos, etmp, rowptr, esrc, edst);

  wconv_kernel   <<<(128*KD + 255)/256, 256, 0, stream>>>(W1, Wmu, Wst, Wb1, Wb2);

  mmt1_kernel  <<<(N_NODES+63)/64, 256, 0, stream>>>(x, Wb1, as1v, ad1v, xpb1, as1, ad1);
  wcalc_kernel <<<(ET+255)/256, 256, 0, stream>>>(esrc, edst, as1, ad1, wedge);
  agg1_kernel  <<<(N_NODES+3)/4, 256, 0, stream>>>(rowptr, esrc, wedge, (const uint4*)xpb1, b1, (uint4*)hb);

  mmt2_kernel  <<<(N_NODES+63)/64, 256, 0, stream>>>(hb, Wb2, asmu, admu, asst, adst, xpb1, as2, ad2);
  wcalc_kernel <<<(ET+255)/256, 256, 0, stream>>>(esrc, edst, as2, ad2, wedge);
  agg2_kernel  <<<(N_NODES+3)/4, 256, 0, stream>>>(rowptr, esrc, wedge, (const uint4*)xpb2, bmu, bst, out);
}